// Round 5
// baseline (644.394 us; speedup 1.0000x reference)
//
#include <hip/hip_runtime.h>
#include <hip/hip_bf16.h>

// GAT on two 512-node cliques + bipartite cross edges, 5 GATConv layers.
//
// R18: single persistent kernel with a FAST tree barrier.
// Reconciling R13-R17: layer cost is invariant to math variant, occupancy,
// and layout; per-kernel exec is ~1-3us of issue yet totals stay ~166-196us.
// Only consistent model: ~10-13us per dependent dispatch boundary in the
// replayed graph.  R14 (fused, naive single-counter barrier) measured
// 262us fused exec = ~30us real phase work + 5 x ~46us barrier (256
// serialized cross-XCD RMWs on ONE cacheline).  Fix the barrier, keep the
// fusion: 16 padded arrival counters (16-way parallel RMWs, ~1-2us),
// monitor block polls sum==256*epoch, bumps generation (monotone counters,
// no reset race; 2KB memsetAsync re-zeroes per replay).  6 barriers.
// Phase bodies: R13 bucket softmax VERBATIM (absmax-0 verified), planar
// gemm with identical FMA parity order (R17-verified), mm2/att2 verbatim.

typedef __hip_bfloat16 bf16;

__device__ __forceinline__ float b2f(bf16 x) { return __bfloat162float(x); }

__device__ __forceinline__ int detect_bf16(const void* desc1) {
  const unsigned* u = (const unsigned*)desc1;
  int hits = 0;
#pragma unroll 8
  for (int i = 0; i < 256; ++i) {
    unsigned e = (u[i] >> 7) & 0xFFu;
    hits += (e >= 100u && e <= 140u) ? 1 : 0;
  }
  return hits >= 200 ? 1 : 0;
}

__device__ __forceinline__ float load_in(const void* p, int i, int bf) {
  return bf ? b2f(((const bf16*)p)[i]) : ((const float*)p)[i];
}

// ------------------------------------------------------ grid barrier ----
// bar[g*16] for g=0..15: arrival counters (64B apart); bar[256]: generation.
// Monotone counts: barrier e complete when sum == 256*e.  Zeroed by a
// memsetAsync before each launch (graph node), so replays are safe.
__device__ __forceinline__ void grid_sync(unsigned* bar, int bid, unsigned e) {
  __syncthreads();
  if (threadIdx.x == 0) {
    __threadfence();  // make this block's phase writes agent-visible
    atomicAdd(&bar[(bid & 15) * 16], 1u);
    if (bid == 0) {
      for (;;) {
        unsigned s = 0;
#pragma unroll
        for (int g = 0; g < 16; ++g)
          s += __hip_atomic_load(&bar[g * 16], __ATOMIC_RELAXED,
                                 __HIP_MEMORY_SCOPE_AGENT);
        if (s >= 256u * e) break;
        __builtin_amdgcn_s_sleep(2);
      }
      __hip_atomic_store(&bar[256], e, __ATOMIC_RELEASE,
                         __HIP_MEMORY_SCOPE_AGENT);
    } else {
      while (__hip_atomic_load(&bar[256], __ATOMIC_ACQUIRE,
                               __HIP_MEMORY_SCOPE_AGENT) < e)
        __builtin_amdgcn_s_sleep(2);
    }
    __threadfence();
  }
  __syncthreads();
}

// ------------------------------------------------------- GAT layer phase ----
// block = (S<<7)|hd, 512 threads.  Phase A: per-thread node dot from planar
// xt (coalesced per k) with W column in LDS; FMA parity order identical to
// the verified kernels (k even->acc0, odd->acc1).  Phase B: R13 bucket
// softmax VERBATIM.  Output written planar (coalesced).
template <int CROSS>
__device__ __forceinline__ void layer_phase(
    char* smem, float* wcol, const float* __restrict__ xt_in,
    float* __restrict__ xt_out, const float* __restrict__ W1t,
    const float* __restrict__ vecs, int bid) {
  float*    sS      = (float*)(smem);            // 512 f
  float*    sH      = (float*)(smem + 2048);     // 512 f
  unsigned* hA      = (unsigned*)(smem + 4096);  // 512 u
  unsigned* ISb     = (unsigned*)(smem + 6144);  // 512 u
  unsigned* binNext = (unsigned*)(smem + 8192);  // 512 u
  float2*   PRE     = (float2*)(smem + 10240);   // 512 f2
  float2*   SUF     = (float2*)(smem + 14336);   // 512 f2
  float*    red     = (float*)(smem + 18432);    // 16 f
  unsigned* wTot    = (unsigned*)(smem + 18496); // 8 u
  float2*   preTot  = (float2*)(smem + 18528);   // 8 f2
  float2*   sufTot  = (float2*)(smem + 18592);   // 8 f2

  const int tid  = threadIdx.x;
  const int lane = tid & 63;
  const int wave = tid >> 6;
  const int hd   = bid & 127;
  const int S    = bid >> 7;
  const int D    = CROSS ? (1 - S) : S;
  const float a_src = vecs[hd], a_dst = vecs[128 + hd], bias = vecs[256 + hd];

  // Phase A: stage W column, per-thread dot(s).
  if (tid < 32) ((float4*)wcol)[tid] = ((const float4*)(W1t + hd * 128))[tid];
  __syncthreads();
  float acc0 = 0.f, acc1 = 0.f, accD0 = 0.f, accD1 = 0.f;
  {
    const int nS = S * 512 + tid;
    const int nD = D * 512 + tid;
    for (int k0 = 0; k0 < 128; k0 += 8) {
      float xs[8], xd[8];
#pragma unroll
      for (int u = 0; u < 8; ++u) {
        xs[u] = xt_in[(k0 + u) * 1024 + nS];
        if (CROSS) xd[u] = xt_in[(k0 + u) * 1024 + nD];
      }
#pragma unroll
      for (int u = 0; u < 8; u += 2) {
        acc0 = fmaf(xs[u],     wcol[k0 + u],     acc0);
        acc1 = fmaf(xs[u + 1], wcol[k0 + u + 1], acc1);
        if (CROSS) {
          accD0 = fmaf(xd[u],     wcol[k0 + u],     accD0);
          accD1 = fmaf(xd[u + 1], wcol[k0 + u + 1], accD1);
        }
      }
    }
  }
  const float h_src = acc0 + acc1;
  const float h_dst = CROSS ? (accD0 + accD1) : h_src;
  const float s_own = h_src * a_src;
  const float d_own = h_dst * a_dst;

  // B1: block min/max of s; zero hist.
  {
    float mnw = s_own, mxw = s_own;
#pragma unroll
    for (int off = 32; off > 0; off >>= 1) {
      mnw = fminf(mnw, __shfl_down(mnw, off));
      mxw = fmaxf(mxw, __shfl_down(mxw, off));
    }
    if (lane == 0) { red[wave] = mnw; red[8 + wave] = mxw; }
  }
  hA[tid] = 0;
  binNext[tid] = 0;
  __syncthreads();                                        // (1)
  const float mn = fminf(fminf(fminf(red[0], red[1]), fminf(red[2], red[3])),
                         fminf(fminf(red[4], red[5]), fminf(red[6], red[7])));
  const float mx = fmaxf(fmaxf(fmaxf(red[8], red[9]), fmaxf(red[10], red[11])),
                         fmaxf(fmaxf(red[12], red[13]), fmaxf(red[14], red[15])));
  const float scale = 512.0f / fmaxf(mx - mn, 1e-20f);

  // B2: histogram.
  const int myBin = (int)fminf(fmaxf((s_own - mn) * scale, 0.0f), 511.0f);
  atomicAdd(&hA[myBin], 1u);
  __syncthreads();                                        // (2)

  // B3: inclusive scan of hist.
  {
    unsigned v = hA[tid];
#pragma unroll
    for (int off = 1; off < 64; off <<= 1) {
      unsigned u = __shfl_up(v, off);
      if (lane >= off) v += u;
    }
    if (lane == 63) wTot[wave] = v;
    __syncthreads();                                      // (3)
    unsigned pre = 0;
#pragma unroll
    for (int w = 0; w < 8; ++w) pre += (w < wave) ? wTot[w] : 0u;
    ISb[tid] = v + pre;
    __syncthreads();                                      // (4)
  }

  // B4: scatter into bucket order.
  {
    unsigned base = myBin ? ISb[myBin - 1] : 0u;
    unsigned pos = base + atomicAdd(&binNext[myBin], 1u);
    sS[pos] = s_own;
    sH[pos] = h_src;
  }
  __syncthreads();                                        // (5)

  // B5: prefix/suffix pairs.
  {
    const float sv = sS[tid];
    const float hv = sH[tid];
    const float e1 = __expf(sv), e2 = __expf(0.2f * sv);
    float p0 = e2, p1 = e2 * hv;
    float q0 = e1, q1 = e1 * hv;
#pragma unroll
    for (int off = 1; off < 64; off <<= 1) {
      float u0 = __shfl_up(p0, off), u1 = __shfl_up(p1, off);
      if (lane >= off) { p0 += u0; p1 += u1; }
      float v0 = __shfl_down(q0, off), v1 = __shfl_down(q1, off);
      if (lane + off < 64) { q0 += v0; q1 += v1; }
    }
    if (lane == 63) preTot[wave] = make_float2(p0, p1);
    if (lane == 0)  sufTot[wave] = make_float2(q0, q1);
    __syncthreads();                                      // (6)
    float a0 = 0.f, a1 = 0.f, b0 = 0.f, b1 = 0.f;
#pragma unroll
    for (int w = 0; w < 8; ++w) {
      float2 pt = preTot[w], st = sufTot[w];
      if (w < wave) { a0 += pt.x; a1 += pt.y; }
      if (w > wave) { b0 += st.x; b1 += st.y; }
    }
    PRE[tid] = make_float2(p0 + a0, p1 + a1);
    SUF[tid] = make_float2(q0 + b0, q1 + b1);
    __syncthreads();                                      // (7)
  }

  // B7: per destination combine.
  {
    const float theta = -d_own;
    int b = (int)fminf(fmaxf((theta - mn) * scale, 0.0f), 511.0f);
    unsigned k0 = b ? ISb[b - 1] : 0u;
    unsigned k1 = ISb[b];
    float F1 = __expf(d_own), F2 = __expf(0.2f * d_own);
    float P2 = 0.f, P2h = 0.f, S1 = 0.f, S1h = 0.f;
    if (k0 > 0)   { float2 t2 = PRE[k0 - 1]; P2 = t2.x; P2h = t2.y; }
    if (k1 < 512) { float2 t2 = SUF[k1];     S1 = t2.x; S1h = t2.y; }
    float den = F1 * S1 + F2 * P2;
    float num = F1 * S1h + F2 * P2h;
    for (unsigned e = k0; e < k1; ++e) {
      float se = sS[e], he = sH[e];
      float p = (se >= theta) ? F1 * __expf(se) : F2 * __expf(0.2f * se);
      den += p;
      num = fmaf(p, he, num);
    }
    if (CROSS) {
      float t = h_dst * a_src + d_own;
      float p = __expf(fmaxf(t, 0.2f * t));
      den += p;
      num = fmaf(p, h_dst, num);
    }
    float o = num / (den + 1e-16f) + bias;
    o = (o > 0.f) ? o : expm1f(o);  // ELU
    xt_out[hd * 1024 + D * 512 + tid] = o;  // planar, coalesced
  }
}

// ------------------------------------------------------ fused persistent ----
__global__ __launch_bounds__(512, 2) void fused_kernel(
    const void* __restrict__ desc1, const void* __restrict__ desc2,
    const void* __restrict__ W1,   const void* __restrict__ as1,
    const void* __restrict__ ad1,  const void* __restrict__ b1,
    const void* __restrict__ W2,   const void* __restrict__ as2,
    const void* __restrict__ ad2,  const void* __restrict__ b2,
    float* __restrict__ xtA, float* __restrict__ xtB,
    float* __restrict__ W1t, float* __restrict__ W2f,
    float* __restrict__ vecs, float* __restrict__ h2,
    float* __restrict__ s2, float* __restrict__ d2,
    void* __restrict__ out, unsigned* __restrict__ bar) {
  __shared__ __align__(16) char smem[18944];
  __shared__ float wcol[128];
  const int tid = threadIdx.x;
  const int bid = blockIdx.x;
  const int bf = detect_bf16(desc1);  // uniform; held in register to P6

  // ---- P0: prep (grid-stride). planar xt, transposed W1t, W2f, vecs ----
  {
    const int total = 131072 + 16384 + 16384 + 6 * 128;
    for (int idx = bid * 512 + tid; idx < total; idx += 256 * 512) {
      if (idx < 131072) {
        int c = idx & 127, n = idx >> 7;  // reads linear in idx
        float v = (n < 512) ? load_in(desc1, idx, bf)
                            : load_in(desc2, idx - 65536, bf);
        xtA[c * 1024 + n] = v;
      } else if (idx < 147456) {
        int i = idx - 131072;             // i = k*128 + hd
        int k = i >> 7, hdd = i & 127;
        W1t[hdd * 128 + k] = load_in(W1, i, bf);
      } else if (idx < 163840) {
        W2f[idx - 147456] = load_in(W2, idx - 147456, bf);
      } else {
        int i = idx - 163840, o = i & 127;
        float v;
        if      (i < 128) v = load_in(as1, o, bf);
        else if (i < 256) v = load_in(ad1, o, bf);
        else if (i < 384) v = load_in(b1, o, bf);
        else if (i < 512) v = load_in(as2, o, bf);
        else if (i < 640) v = load_in(ad2, o, bf);
        else              v = load_in(b2, o, bf);
        vecs[i] = v;
      }
    }
  }
  grid_sync(bar, bid, 1);

  layer_phase<0>(smem, wcol, xtA, xtB, W1t, vecs, bid);  // L1 inside
  grid_sync(bar, bid, 2);
  layer_phase<1>(smem, wcol, xtB, xtA, W1t, vecs, bid);  // L2 cross
  grid_sync(bar, bid, 3);
  layer_phase<0>(smem, wcol, xtA, xtB, W1t, vecs, bid);  // L3 inside
  grid_sync(bar, bid, 4);
  layer_phase<1>(smem, wcol, xtB, xtA, W1t, vecs, bid);  // L4 cross
  grid_sync(bar, bid, 5);

  // ---- P5: mm2.  4 rows/block, 128 cols; planar x reads; LDS reduce ----
  {
    float* rs = (float*)(smem);
    float* rd = (float*)(smem + 2048);
    const int row = bid * 4 + (tid >> 7);
    const int c = tid & 127;
    float acc0 = 0.f, acc1 = 0.f;
    for (int k0 = 0; k0 < 128; k0 += 8) {
      float xb[8];
#pragma unroll
      for (int u = 0; u < 8; ++u) xb[u] = xtA[(k0 + u) * 1024 + row];
#pragma unroll
      for (int u = 0; u < 8; u += 2) {
        acc0 = fmaf(xb[u],     W2f[(k0 + u) * 128 + c],     acc0);
        acc1 = fmaf(xb[u + 1], W2f[(k0 + u + 1) * 128 + c], acc1);
      }
    }
    float acc = acc0 + acc1;
    h2[row * 128 + c] = acc;
    rs[tid] = acc * vecs[384 + c];  // a_src2
    rd[tid] = acc * vecs[512 + c];  // a_dst2
    __syncthreads();
    for (int off = 64; off > 0; off >>= 1) {
      if ((tid & 127) < off) { rs[tid] += rs[tid + off]; rd[tid] += rd[tid + off]; }
      __syncthreads();
    }
    if ((tid & 127) == 0) {
      s2[row] = rs[tid];
      d2[row] = rd[tid];
    }
  }
  grid_sync(bar, bid, 6);

  // ---- P6: att2.  4 dsts/block, one per 128-thread group ----
  {
    float* pT = (float*)(smem);  // pT[j*4 + ld], 2048 floats
    const int dstBase = bid * 4;
    const int srcBase = (dstBase < 512) ? 512 : 0;  // cross edges
    for (int e = tid; e < 2048; e += 512) {
      int j = e >> 2, ld = e & 3;
      float t = s2[srcBase + j] + d2[dstBase + ld];
      pT[e] = __expf(fmaxf(t, 0.2f * t));
    }
    __syncthreads();

    const int c = tid & 127;
    const int g = tid >> 7;            // 0..3 -> dst within block
    const int i0 = dstBase + g;
    float den = 0.f, num = 0.f;
    const float* hrow = h2 + srcBase * 128 + c;
    for (int j0 = 0; j0 < 512; j0 += 8) {
      float hb[8];
#pragma unroll
      for (int u = 0; u < 8; ++u) hb[u] = hrow[(j0 + u) * 128];
#pragma unroll
      for (int u = 0; u < 8; ++u) {
        float p = pT[(j0 + u) * 4 + g];
        den += p;
        num = fmaf(p, hb[u], num);
      }
    }
    // self-loop
    float ts = s2[i0] + d2[i0];
    float ps = __expf(fmaxf(ts, 0.2f * ts));
    den += ps;
    num = fmaf(ps, h2[i0 * 128 + c], num);

    float o = num / (den + 1e-16f) + vecs[640 + c];
    if (bf) ((bf16*)out)[i0 * 128 + c] = __float2bfloat16(o);
    else    ((float*)out)[i0 * 128 + c] = o;
  }
}

// ------------------------------------------------------------- launcher ----
extern "C" void kernel_launch(void* const* d_in, const int* in_sizes, int n_in,
                              void* d_out, int out_size, void* d_ws, size_t ws_size,
                              hipStream_t stream) {
  (void)in_sizes; (void)n_in; (void)out_size; (void)ws_size;
  float* ws   = (float*)d_ws;
  float* xtA  = ws;            // 131072 (planar [ch][node])
  float* xtB  = ws + 131072;   // 131072 (planar [ch][node])
  float* h2   = ws + 262144;   // 131072 (row-major)
  float* W1t  = ws + 393216;   // 16384 (transposed W1)
  float* W2f  = ws + 409600;   // 16384
  float* vecs = ws + 425984;   // 768
  float* s2   = ws + 426752;   // 1024
  float* d2   = ws + 427776;   // 1024
  unsigned* bar = (unsigned*)(ws + 428800);  // 16 padded counters + gen

  hipMemsetAsync(bar, 0, 2048, stream);
  fused_kernel<<<256, 512, 0, stream>>>(
      d_in[0], d_in[1], d_in[2], d_in[3], d_in[4], d_in[5], d_in[6], d_in[7],
      d_in[8], d_in[9], xtA, xtB, W1t, W2f, vecs, h2, s2, d2, d_out, bar);
}

// Round 7
// 510.006 us; speedup vs baseline: 1.2635x; 1.2635x over previous
//
#include <hip/hip_runtime.h>
#include <hip/hip_bf16.h>

// GAT on two 512-node cliques + bipartite cross edges, 5 GATConv layers.
//
// R20 = R19 with the grid barrier made RMW-ONLY.  R18 (RELEASE store +
// ACQUIRE polls) ran but burned 580MB HBM via per-poll buffer_inv; R19
// (RELAXED store + RELAXED polls) hung the container: on CDNA4 the relaxed
// atomic STORE of the generation can sit dirty in block 0's non-coherent
// XCD L2 forever while remote waiters poll the MALL -> infinite spin.
// Atomic RMWs, by contrast, are always performed at the device-coherent
// point (proven: arrival counters were observed in R14/R18).  So: arrival
// = fetch_add(1), gen publish = fetch_add(1), ALL polls = fetch_add(0)
// (MALL-read, no cache invalidate, no store-visibility assumption).
// One threadfence release before arrival + one acquire after exit per
// block per barrier.  Spins BOUNDED so bugs fail verification instead of
// killing the GPU.  Phase bodies byte-identical to R18 (absmax 0.0).

typedef __hip_bfloat16 bf16;

__device__ __forceinline__ float b2f(bf16 x) { return __bfloat162float(x); }

__device__ __forceinline__ int detect_bf16(const void* desc1) {
  const unsigned* u = (const unsigned*)desc1;
  int hits = 0;
#pragma unroll 8
  for (int i = 0; i < 256; ++i) {
    unsigned e = (u[i] >> 7) & 0xFFu;
    hits += (e >= 100u && e <= 140u) ? 1 : 0;
  }
  return hits >= 200 ? 1 : 0;
}

__device__ __forceinline__ float load_in(const void* p, int i, int bf) {
  return bf ? b2f(((const bf16*)p)[i]) : ((const float*)p)[i];
}

// ------------------------------------------------------ grid barrier ----
// bar[g*16] g=0..15: arrival counters (64B apart); bar[256]: generation
// (own cacheline).  Monotone: barrier e complete when sum == 256*e and
// gen >= e.  ALL signal ops are atomic RMWs (device-coherent point);
// polls are fetch_add(0) -- coherent reads with no buffer_inv.
// Counters zeroed by a 2KB memsetAsync before each launch (replay-safe).
__device__ __forceinline__ unsigned rmw_read(unsigned* p) {
  return __hip_atomic_fetch_add(p, 0u, __ATOMIC_RELAXED,
                                __HIP_MEMORY_SCOPE_AGENT);
}

__device__ __forceinline__ void grid_sync(unsigned* bar, int bid, unsigned e) {
  __syncthreads();
  if (threadIdx.x == 0) {
    __threadfence();  // release: make this block's phase writes visible
    __hip_atomic_fetch_add(&bar[(bid & 15) * 16], 1u, __ATOMIC_RELAXED,
                           __HIP_MEMORY_SCOPE_AGENT);
    if (bid == 0) {
      for (int it = 0; it < (1 << 20); ++it) {  // bounded: fail, don't hang
        unsigned s = 0;
#pragma unroll
        for (int g = 0; g < 16; ++g) s += rmw_read(&bar[g * 16]);
        if (s >= 256u * e) break;
        __builtin_amdgcn_s_sleep(2);
      }
      __hip_atomic_fetch_add(&bar[256], 1u, __ATOMIC_RELAXED,
                             __HIP_MEMORY_SCOPE_AGENT);  // gen: e-1 -> e
    } else {
      for (int it = 0; it < (1 << 20); ++it) {  // bounded: fail, don't hang
        if (rmw_read(&bar[256]) >= e) break;
        __builtin_amdgcn_s_sleep(8);
      }
    }
    __threadfence();  // acquire: drop stale lines before next phase reads
  }
  __syncthreads();
}

// ------------------------------------------------------- GAT layer phase ----
// block = (S<<7)|hd, 512 threads.  Phase A: per-thread node dot from planar
// xt (coalesced per k) with W column in LDS; FMA parity order identical to
// the verified kernels (k even->acc0, odd->acc1).  Phase B: R13 bucket
// softmax VERBATIM.  Output written planar (coalesced).
template <int CROSS>
__device__ __forceinline__ void layer_phase(
    char* smem, float* wcol, const float* __restrict__ xt_in,
    float* __restrict__ xt_out, const float* __restrict__ W1t,
    const float* __restrict__ vecs, int bid) {
  float*    sS      = (float*)(smem);            // 512 f
  float*    sH      = (float*)(smem + 2048);     // 512 f
  unsigned* hA      = (unsigned*)(smem + 4096);  // 512 u
  unsigned* ISb     = (unsigned*)(smem + 6144);  // 512 u
  unsigned* binNext = (unsigned*)(smem + 8192);  // 512 u
  float2*   PRE     = (float2*)(smem + 10240);   // 512 f2
  float2*   SUF     = (float2*)(smem + 14336);   // 512 f2
  float*    red     = (float*)(smem + 18432);    // 16 f
  unsigned* wTot    = (unsigned*)(smem + 18496); // 8 u
  float2*   preTot  = (float2*)(smem + 18528);   // 8 f2
  float2*   sufTot  = (float2*)(smem + 18592);   // 8 f2

  const int tid  = threadIdx.x;
  const int lane = tid & 63;
  const int wave = tid >> 6;
  const int hd   = bid & 127;
  const int S    = bid >> 7;
  const int D    = CROSS ? (1 - S) : S;
  const float a_src = vecs[hd], a_dst = vecs[128 + hd], bias = vecs[256 + hd];

  // Phase A: stage W column, per-thread dot(s).
  if (tid < 32) ((float4*)wcol)[tid] = ((const float4*)(W1t + hd * 128))[tid];
  __syncthreads();
  float acc0 = 0.f, acc1 = 0.f, accD0 = 0.f, accD1 = 0.f;
  {
    const int nS = S * 512 + tid;
    const int nD = D * 512 + tid;
    for (int k0 = 0; k0 < 128; k0 += 8) {
      float xs[8], xd[8];
#pragma unroll
      for (int u = 0; u < 8; ++u) {
        xs[u] = xt_in[(k0 + u) * 1024 + nS];
        if (CROSS) xd[u] = xt_in[(k0 + u) * 1024 + nD];
      }
#pragma unroll
      for (int u = 0; u < 8; u += 2) {
        acc0 = fmaf(xs[u],     wcol[k0 + u],     acc0);
        acc1 = fmaf(xs[u + 1], wcol[k0 + u + 1], acc1);
        if (CROSS) {
          accD0 = fmaf(xd[u],     wcol[k0 + u],     accD0);
          accD1 = fmaf(xd[u + 1], wcol[k0 + u + 1], accD1);
        }
      }
    }
  }
  const float h_src = acc0 + acc1;
  const float h_dst = CROSS ? (accD0 + accD1) : h_src;
  const float s_own = h_src * a_src;
  const float d_own = h_dst * a_dst;

  // B1: block min/max of s; zero hist.
  {
    float mnw = s_own, mxw = s_own;
#pragma unroll
    for (int off = 32; off > 0; off >>= 1) {
      mnw = fminf(mnw, __shfl_down(mnw, off));
      mxw = fmaxf(mxw, __shfl_down(mxw, off));
    }
    if (lane == 0) { red[wave] = mnw; red[8 + wave] = mxw; }
  }
  hA[tid] = 0;
  binNext[tid] = 0;
  __syncthreads();                                        // (1)
  const float mn = fminf(fminf(fminf(red[0], red[1]), fminf(red[2], red[3])),
                         fminf(fminf(red[4], red[5]), fminf(red[6], red[7])));
  const float mx = fmaxf(fmaxf(fmaxf(red[8], red[9]), fmaxf(red[10], red[11])),
                         fmaxf(fmaxf(red[12], red[13]), fmaxf(red[14], red[15])));
  const float scale = 512.0f / fmaxf(mx - mn, 1e-20f);

  // B2: histogram.
  const int myBin = (int)fminf(fmaxf((s_own - mn) * scale, 0.0f), 511.0f);
  atomicAdd(&hA[myBin], 1u);
  __syncthreads();                                        // (2)

  // B3: inclusive scan of hist.
  {
    unsigned v = hA[tid];
#pragma unroll
    for (int off = 1; off < 64; off <<= 1) {
      unsigned u = __shfl_up(v, off);
      if (lane >= off) v += u;
    }
    if (lane == 63) wTot[wave] = v;
    __syncthreads();                                      // (3)
    unsigned pre = 0;
#pragma unroll
    for (int w = 0; w < 8; ++w) pre += (w < wave) ? wTot[w] : 0u;
    ISb[tid] = v + pre;
    __syncthreads();                                      // (4)
  }

  // B4: scatter into bucket order.
  {
    unsigned base = myBin ? ISb[myBin - 1] : 0u;
    unsigned pos = base + atomicAdd(&binNext[myBin], 1u);
    sS[pos] = s_own;
    sH[pos] = h_src;
  }
  __syncthreads();                                        // (5)

  // B5: prefix/suffix pairs.
  {
    const float sv = sS[tid];
    const float hv = sH[tid];
    const float e1 = __expf(sv), e2 = __expf(0.2f * sv);
    float p0 = e2, p1 = e2 * hv;
    float q0 = e1, q1 = e1 * hv;
#pragma unroll
    for (int off = 1; off < 64; off <<= 1) {
      float u0 = __shfl_up(p0, off), u1 = __shfl_up(p1, off);
      if (lane >= off) { p0 += u0; p1 += u1; }
      float v0 = __shfl_down(q0, off), v1 = __shfl_down(q1, off);
      if (lane + off < 64) { q0 += v0; q1 += v1; }
    }
    if (lane == 63) preTot[wave] = make_float2(p0, p1);
    if (lane == 0)  sufTot[wave] = make_float2(q0, q1);
    __syncthreads();                                      // (6)
    float a0 = 0.f, a1 = 0.f, b0 = 0.f, b1 = 0.f;
#pragma unroll
    for (int w = 0; w < 8; ++w) {
      float2 pt = preTot[w], st = sufTot[w];
      if (w < wave) { a0 += pt.x; a1 += pt.y; }
      if (w > wave) { b0 += st.x; b1 += st.y; }
    }
    PRE[tid] = make_float2(p0 + a0, p1 + a1);
    SUF[tid] = make_float2(q0 + b0, q1 + b1);
    __syncthreads();                                      // (7)
  }

  // B7: per destination combine.
  {
    const float theta = -d_own;
    int b = (int)fminf(fmaxf((theta - mn) * scale, 0.0f), 511.0f);
    unsigned k0 = b ? ISb[b - 1] : 0u;
    unsigned k1 = ISb[b];
    float F1 = __expf(d_own), F2 = __expf(0.2f * d_own);
    float P2 = 0.f, P2h = 0.f, S1 = 0.f, S1h = 0.f;
    if (k0 > 0)   { float2 t2 = PRE[k0 - 1]; P2 = t2.x; P2h = t2.y; }
    if (k1 < 512) { float2 t2 = SUF[k1];     S1 = t2.x; S1h = t2.y; }
    float den = F1 * S1 + F2 * P2;
    float num = F1 * S1h + F2 * P2h;
    for (unsigned e = k0; e < k1; ++e) {
      float se = sS[e], he = sH[e];
      float p = (se >= theta) ? F1 * __expf(se) : F2 * __expf(0.2f * se);
      den += p;
      num = fmaf(p, he, num);
    }
    if (CROSS) {
      float t = h_dst * a_src + d_own;
      float p = __expf(fmaxf(t, 0.2f * t));
      den += p;
      num = fmaf(p, h_dst, num);
    }
    float o = num / (den + 1e-16f) + bias;
    o = (o > 0.f) ? o : expm1f(o);  // ELU
    xt_out[hd * 1024 + D * 512 + tid] = o;  // planar, coalesced
  }
}

// ------------------------------------------------------ fused persistent ----
__global__ __launch_bounds__(512, 2) void fused_kernel(
    const void* __restrict__ desc1, const void* __restrict__ desc2,
    const void* __restrict__ W1,   const void* __restrict__ as1,
    const void* __restrict__ ad1,  const void* __restrict__ b1,
    const void* __restrict__ W2,   const void* __restrict__ as2,
    const void* __restrict__ ad2,  const void* __restrict__ b2,
    float* __restrict__ xtA, float* __restrict__ xtB,
    float* __restrict__ W1t, float* __restrict__ W2f,
    float* __restrict__ vecs, float* __restrict__ h2,
    float* __restrict__ s2, float* __restrict__ d2,
    void* __restrict__ out, unsigned* __restrict__ bar) {
  __shared__ __align__(16) char smem[18944];
  __shared__ float wcol[128];
  const int tid = threadIdx.x;
  const int bid = blockIdx.x;
  const int bf = detect_bf16(desc1);  // uniform; held in register to P6

  // ---- P0: prep (grid-stride). planar xt, transposed W1t, W2f, vecs ----
  {
    const int total = 131072 + 16384 + 16384 + 6 * 128;
    for (int idx = bid * 512 + tid; idx < total; idx += 256 * 512) {
      if (idx < 131072) {
        int c = idx & 127, n = idx >> 7;  // reads linear in idx
        float v = (n < 512) ? load_in(desc1, idx, bf)
                            : load_in(desc2, idx - 65536, bf);
        xtA[c * 1024 + n] = v;
      } else if (idx < 147456) {
        int i = idx - 131072;             // i = k*128 + hd
        int k = i >> 7, hdd = i & 127;
        W1t[hdd * 128 + k] = load_in(W1, i, bf);
      } else if (idx < 163840) {
        W2f[idx - 147456] = load_in(W2, idx - 147456, bf);
      } else {
        int i = idx - 163840, o = i & 127;
        float v;
        if      (i < 128) v = load_in(as1, o, bf);
        else if (i < 256) v = load_in(ad1, o, bf);
        else if (i < 384) v = load_in(b1, o, bf);
        else if (i < 512) v = load_in(as2, o, bf);
        else if (i < 640) v = load_in(ad2, o, bf);
        else              v = load_in(b2, o, bf);
        vecs[i] = v;
      }
    }
  }
  grid_sync(bar, bid, 1);

  layer_phase<0>(smem, wcol, xtA, xtB, W1t, vecs, bid);  // L1 inside
  grid_sync(bar, bid, 2);
  layer_phase<1>(smem, wcol, xtB, xtA, W1t, vecs, bid);  // L2 cross
  grid_sync(bar, bid, 3);
  layer_phase<0>(smem, wcol, xtA, xtB, W1t, vecs, bid);  // L3 inside
  grid_sync(bar, bid, 4);
  layer_phase<1>(smem, wcol, xtB, xtA, W1t, vecs, bid);  // L4 cross
  grid_sync(bar, bid, 5);

  // ---- P5: mm2.  4 rows/block, 128 cols; planar x reads; LDS reduce ----
  {
    float* rs = (float*)(smem);
    float* rd = (float*)(smem + 2048);
    const int row = bid * 4 + (tid >> 7);
    const int c = tid & 127;
    float acc0 = 0.f, acc1 = 0.f;
    for (int k0 = 0; k0 < 128; k0 += 8) {
      float xb[8];
#pragma unroll
      for (int u = 0; u < 8; ++u) xb[u] = xtA[(k0 + u) * 1024 + row];
#pragma unroll
      for (int u = 0; u < 8; u += 2) {
        acc0 = fmaf(xb[u],     W2f[(k0 + u) * 128 + c],     acc0);
        acc1 = fmaf(xb[u + 1], W2f[(k0 + u + 1) * 128 + c], acc1);
      }
    }
    float acc = acc0 + acc1;
    h2[row * 128 + c] = acc;
    rs[tid] = acc * vecs[384 + c];  // a_src2
    rd[tid] = acc * vecs[512 + c];  // a_dst2
    __syncthreads();
    for (int off = 64; off > 0; off >>= 1) {
      if ((tid & 127) < off) { rs[tid] += rs[tid + off]; rd[tid] += rd[tid + off]; }
      __syncthreads();
    }
    if ((tid & 127) == 0) {
      s2[row] = rs[tid];
      d2[row] = rd[tid];
    }
  }
  grid_sync(bar, bid, 6);

  // ---- P6: att2.  4 dsts/block, one per 128-thread group ----
  {
    float* pT = (float*)(smem);  // pT[j*4 + ld], 2048 floats
    const int dstBase = bid * 4;
    const int srcBase = (dstBase < 512) ? 512 : 0;  // cross edges
    for (int e = tid; e < 2048; e += 512) {
      int j = e >> 2, ld = e & 3;
      float t = s2[srcBase + j] + d2[dstBase + ld];
      pT[e] = __expf(fmaxf(t, 0.2f * t));
    }
    __syncthreads();

    const int c = tid & 127;
    const int g = tid >> 7;            // 0..3 -> dst within block
    const int i0 = dstBase + g;
    float den = 0.f, num = 0.f;
    const float* hrow = h2 + srcBase * 128 + c;
    for (int j0 = 0; j0 < 512; j0 += 8) {
      float hb[8];
#pragma unroll
      for (int u = 0; u < 8; ++u) hb[u] = hrow[(j0 + u) * 128];
#pragma unroll
      for (int u = 0; u < 8; ++u) {
        float p = pT[(j0 + u) * 4 + g];
        den += p;
        num = fmaf(p, hb[u], num);
      }
    }
    // self-loop
    float ts = s2[i0] + d2[i0];
    float ps = __expf(fmaxf(ts, 0.2f * ts));
    den += ps;
    num = fmaf(ps, h2[i0 * 128 + c], num);

    float o = num / (den + 1e-16f) + vecs[640 + c];
    if (bf) ((bf16*)out)[i0 * 128 + c] = __float2bfloat16(o);
    else    ((float*)out)[i0 * 128 + c] = o;
  }
}

// ------------------------------------------------------------- launcher ----
extern "C" void kernel_launch(void* const* d_in, const int* in_sizes, int n_in,
                              void* d_out, int out_size, void* d_ws, size_t ws_size,
                              hipStream_t stream) {
  (void)in_sizes; (void)n_in; (void)out_size; (void)ws_size;
  float* ws   = (float*)d_ws;
  float* xtA  = ws;            // 131072 (planar [ch][node])
  float* xtB  = ws + 131072;   // 131072 (planar [ch][node])
  float* h2   = ws + 262144;   // 131072 (row-major)
  float* W1t  = ws + 393216;   // 16384 (transposed W1)
  float* W2f  = ws + 409600;   // 16384
  float* vecs = ws + 425984;   // 768
  float* s2   = ws + 426752;   // 1024
  float* d2   = ws + 427776;   // 1024
  unsigned* bar = (unsigned*)(ws + 428800);  // 16 padded counters + gen

  hipMemsetAsync(bar, 0, 2048, stream);
  fused_kernel<<<256, 512, 0, stream>>>(
      d_in[0], d_in[1], d_in[2], d_in[3], d_in[4], d_in[5], d_in[6], d_in[7],
      d_in[8], d_in[9], xtA, xtB, W1t, W2f, vecs, h2, s2, d2, d_out, bar);
}